// Round 4
// baseline (43.144 us; speedup 1.0000x reference)
//
#include <hip/hip_runtime.h>
#include <math.h>

// DecodeBox: input [B=4, A*10=30, D=64, H=64, W=64] f32
// output [B, A*D*H*W, 10] f32
// attrs out: bx, by, bz, bl, conf, cls0..cls4
//   bx = (sigmoid(p0) + w) * 4 ; by = (sigmoid(p1) + h) * 4 ; bz = (sigmoid(p2) + d) * 4
//   bl = exp(p3) * anchor_w[a]   (anchor {10,16,33}; /stride*stride cancels)
//   conf/cls = sigmoid
//
// v4: 8 rows/thread -> 20 batched float4 loads (sched_barrier keeps them
// issued together for MLP); elementwise transform IN PLACE (no second reg
// array); 4-pass LDS-staged transpose with XOR swizzle (conflict-free stage
// writes); nontemporal flush stores so the streamed output doesn't evict the
// L3-resident input between replays.

typedef float v4f __attribute__((ext_vector_type(4)));

constexpr int A_NUM  = 3;
constexpr int ATTRS  = 10;
constexpr int DD = 64, HH = 64, WW = 64;
constexpr int SPATIAL = DD * HH * WW;   // 262144 = 2^18
constexpr int BLOCK = 256;
constexpr int ROWS_PER_THREAD = 8;
constexpr int CHUNK_ROWS = BLOCK * ROWS_PER_THREAD;          // 2048 rows/block
constexpr int CHUNK_VEC4 = CHUNK_ROWS * ATTRS / 4;           // 5120 float4 = 80 KB out/block
constexpr int PASS_VEC4  = CHUNK_VEC4 / 4;                   // 1280 float4 = 20 KB LDS

__device__ __forceinline__ float sigmoidf_fast(float x) {
    return 1.0f / (1.0f + __expf(-x));
}

__global__ __launch_bounds__(256) void decode_box_kernel(const float* __restrict__ in,
                                                         float* __restrict__ out) {
    __shared__ v4f tile[PASS_VEC4];

    int tid = threadIdx.x;
    int wid = tid >> 6;
    int lt  = tid & 63;

    int idx = (blockIdx.x * BLOCK + tid) << 3;   // first of 8 consecutive rows
    int s   = idx & (SPATIAL - 1);
    int ba  = idx >> 18;                         // b*3 + a
    int a   = ba % A_NUM;
    int w   = s & (WW - 1);
    int h   = (s >> 6) & (HH - 1);
    int d   = s >> 12;

    const float* base = in + (size_t)ba * ATTRS * SPATIAL + s;

    // ---- batched loads: 20 float4, all issued before any compute ----
    v4f L[20];
#pragma unroll
    for (int k = 0; k < ATTRS; ++k) {
        L[2 * k]     = *reinterpret_cast<const v4f*>(base + (size_t)k * SPATIAL);
        L[2 * k + 1] = *reinterpret_cast<const v4f*>(base + (size_t)k * SPATIAL + 4);
    }
    __builtin_amdgcn_sched_barrier(0);

    // ---- elementwise transform in place: L[2k+half][c] = out attr k, row j=4*half+c ----
    float aw = (a == 0) ? 10.0f : (a == 1 ? 16.0f : 33.0f);
    float fw = (float)w * 4.0f;
    float fh = (float)h * 4.0f;
    float fd = (float)d * 4.0f;

#pragma unroll
    for (int k = 0; k < ATTRS; ++k) {
#pragma unroll
        for (int half = 0; half < 2; ++half) {
#pragma unroll
            for (int c = 0; c < 4; ++c) {
                int j = half * 4 + c;   // row offset within thread (0..7)
                float x = L[2 * k + half][c];
                float r;
                if      (k == 0) r = sigmoidf_fast(x) * 4.0f + fw + (float)j * 4.0f;
                else if (k == 1) r = sigmoidf_fast(x) * 4.0f + fh;
                else if (k == 2) r = sigmoidf_fast(x) * 4.0f + fd;
                else if (k == 3) r = __expf(x) * aw;
                else             r = sigmoidf_fast(x);
                L[2 * k + half][c] = r;
            }
        }
    }

    // ---- 4-pass LDS transpose + coalesced nontemporal flush ----
    // Thread owns output float4s [20*t_global, 20*t_global+20); wave p's 64
    // threads exactly cover pass p's 1280-float4 range.
    v4f* o4 = reinterpret_cast<v4f*>(out) + (size_t)blockIdx.x * CHUNK_VEC4;

#pragma unroll
    for (int p = 0; p < 4; ++p) {
        if (wid == p) {
#pragma unroll
            for (int i = 0; i < 20; ++i) {
                v4f v;
#pragma unroll
                for (int c = 0; c < 4; ++c) {
                    int g = 4 * i + c;      // float offset within this thread's 80
                    int j = g / ATTRS;      // row 0..7
                    int k = g % ATTRS;      // attr
                    v[c] = L[2 * k + (j >> 2)][j & 3];
                }
                int jj = lt * 20 + i;
                tile[jj ^ (lt & 7)] = v;    // XOR swizzle: conflict-free banks
            }
        }
        __syncthreads();
#pragma unroll
        for (int i = 0; i < PASS_VEC4 / BLOCK; ++i) {   // 5 float4 per thread
            int j = i * BLOCK + tid;
            unsigned q = (unsigned)j / 20u;             // same swizzle, reader side
            v4f v = tile[j ^ (int)(q & 7u)];
            __builtin_nontemporal_store(v, &o4[p * PASS_VEC4 + j]);
        }
        if (p < 3) __syncthreads();
    }
}

extern "C" void kernel_launch(void* const* d_in, const int* in_sizes, int n_in,
                              void* d_out, int out_size, void* d_ws, size_t ws_size,
                              hipStream_t stream) {
    const float* in = (const float*)d_in[0];
    float* out = (float*)d_out;

    int total  = in_sizes[0] / ATTRS;          // B*A*SPATIAL = 3,145,728 rows
    int blocks = total / CHUNK_ROWS;           // 1536 blocks

    decode_box_kernel<<<blocks, BLOCK, 0, stream>>>(in, out);
}